// Round 13
// baseline (351.823 us; speedup 1.0000x reference)
//
#include <hip/hip_runtime.h>
#include <hip/hip_fp16.h>
#include <math.h>

// DiagonalLSTM: B=8, Cin=HID=128, H=64, W=64, K=2, T = 2W-1 = 127 steps.
//
// Round 13 design (round 12 + per-step VALU cuts in lstm):
//   - bias (b_is+b_ss) folded into zph during zpre; bias-only slot appended
//     at pos=B*H*W serves out-of-band steps via pointer select -> gate math
//     is z = acc + cvt_f32_f16(zh), no per-step bias adds / zero-fills.
//   - incremental pointers: zp (+=512 halfs/step), hx consumer & producer
//     (+=2048 u64/step), out (4 ptrs, +=4 per flush) -> no per-step 64-bit
//     address recomputation.
//   - otherwise the proven R10/R12 loop: 32 blocks x 512 thr, sentinel hx
//     exchange (fire-and-forget, data==flag, zero drains), 1 barrier/step,
//     boundary+zp prefetched 1 step ahead, MFMA intrinsics, reg-buffered out.

#define HID 128
#define BB 8
#define HH 64
#define WW 64
#define TT 127

typedef _Float16 v8h __attribute__((ext_vector_type(8)));
typedef float v4f __attribute__((ext_vector_type(4)));

#define SENT64 0xFFFFFFFFFFFFFFFFULL  // 4x f16 -NaN (memset 0xFF pattern)

__device__ __forceinline__ float fsig(float x) {
  x = __builtin_fmaxf(__builtin_fminf(x, 30.f), -30.f);
  float e = __builtin_amdgcn_exp2f(x * -1.44269504f);
  return __builtin_amdgcn_rcpf(1.f + e);
}
__device__ __forceinline__ float ftanh_(float x) {
  x = __builtin_fmaxf(__builtin_fminf(x, 15.f), -15.f);
  float e = __builtin_amdgcn_exp2f(x * 2.88539009f);
  return (e - 1.f) * __builtin_amdgcn_rcpf(e + 1.f);
}

// ---- prep_w2: w_ss frags + w_is frags + zph bias slot + bsum512 ----
__global__ __launch_bounds__(256) void prep_w2(const float* __restrict__ w_ss,
                                               const float* __restrict__ w_is,
                                               const float* __restrict__ b_is,
                                               const float* __restrict__ b_ss,
                                               _Float16* __restrict__ wp,
                                               _Float16* __restrict__ wisa,
                                               __half* __restrict__ zph,
                                               float* __restrict__ bsum512) {
  int idx = blockIdx.x * 256 + threadIdx.x;
  if (idx < 131072) {
    // w_ss -> Wcat(512x256) A-frags: wp[(((mt*8+kt)*64+L)*8+j)]
    int j = idx & 7;
    int L = (idx >> 3) & 63;
    int kt = (idx >> 9) & 7;
    int mt = idx >> 12;  // 0..31
    int O = mt * 16 + (L & 15);
    int k = kt * 32 + ((L >> 4) & 3) * 8 + j;
    float v = (k < 128) ? w_ss[(size_t)O * 256 + k * 2]
                        : w_ss[(size_t)O * 256 + (k - 128) * 2 + 1];
    wp[idx] = (_Float16)v;
  } else if (idx < 196608) {
    // w_is (512x128) A-frags: wisa[(((mt*4+kt)*64+L)*8+j)]
    int i2 = idx - 131072;
    int j = i2 & 7;
    int L = (i2 >> 3) & 63;
    int kt = (i2 >> 9) & 3;
    int mt = i2 >> 11;  // 0..31
    int O = mt * 16 + (L & 15);
    int k = kt * 32 + ((L >> 4) & 3) * 8 + j;
    wisa[i2] = (_Float16)w_is[(size_t)O * 128 + k];
  } else if (idx < 197120) {
    // zph bias slot: layout idx2 = (u>>2)*16 + g*4 + (u&3)
    int idx2 = idx - 196608;  // 0..511
    int g = (idx2 >> 2) & 3;
    int u = (idx2 >> 4) * 4 + (idx2 & 3);
    int O = g * 128 + u;
    zph[(size_t)BB * HH * WW * 512 + idx2] = __float2half(b_is[O] + b_ss[O]);
  } else if (idx < 197632) {
    int O = idx - 197120;
    bsum512[O] = b_is[O] + b_ss[O];
  }
}

// ---- zpre_mfma: zph[pos*512 + (u>>2)*16 + g*4 + (u&3)] = z + bias ----
__global__ __launch_bounds__(256) void zpre_mfma(const float* __restrict__ x,
                                                 const _Float16* __restrict__ wisa,
                                                 const float* __restrict__ bsum512,
                                                 __half* __restrict__ zph) {
  const int b = blockIdx.x >> 6;
  const int r = blockIdx.x & 63;
  const int tid = threadIdx.x;
  const int wv = tid >> 6;  // 0..3 -> ntile
  const int L = tid & 63;
  const int quad = L >> 4;
  const int l15 = L & 15;

  __shared__ _Float16 xt[64][136];  // [w][c] f16, padded
  __shared__ float bs[512];

  if (tid < 128) {
    *(float4*)&bs[tid * 4] = *(const float4*)&bsum512[tid * 4];
  }
  // stage x(b,:,r,:) -> xt transposed; coalesced 16-lane c-row reads
  {
    const int cw = tid >> 4;        // c within pass
    const int w4 = (tid & 15) * 4;  // w base
#pragma unroll
    for (int p = 0; p < 8; p++) {
      int c = p * 16 + cw;
      float4 v = *(const float4*)&x[(((size_t)b * 128 + c) * HH + r) * WW + w4];
      xt[w4 + 0][c] = (_Float16)v.x;
      xt[w4 + 1][c] = (_Float16)v.y;
      xt[w4 + 2][c] = (_Float16)v.z;
      xt[w4 + 3][c] = (_Float16)v.w;
    }
  }
  __syncthreads();

  const int wcol = wv * 16 + l15;  // B-side n
  v8h bf[4];
#pragma unroll
  for (int kt = 0; kt < 4; kt++)
    bf[kt] = *(const v8h*)&xt[wcol][kt * 32 + quad * 8];

  const size_t pos = ((size_t)b * HH + r) * WW + wcol;
  const v8h* wa8 = (const v8h*)wisa;

#pragma unroll 4
  for (int mt = 0; mt < 32; mt++) {
    v4f acc = (v4f){0.f, 0.f, 0.f, 0.f};
#pragma unroll
    for (int kt = 0; kt < 4; kt++) {
      v8h af = wa8[((size_t)mt * 4 + kt) * 64 + L];
      acc = __builtin_amdgcn_mfma_f32_16x16x32_f16(af, bf[kt], acc, 0, 0, 0);
    }
    // O = mt*16 + quad*4 + reg; add bias, pack, store
    float4 bv = *(float4*)&bs[mt * 16 + quad * 4];
    __half2 lo = __floats2half2_rn(acc[0] + bv.x, acc[1] + bv.y);
    __half2 hi = __floats2half2_rn(acc[2] + bv.z, acc[3] + bv.w);
    uint2 pk;
    pk.x = *(unsigned*)&lo;
    pk.y = *(unsigned*)&hi;
    *(uint2*)&zph[pos * 512 + ((mt & 7) * 4 + quad) * 16 + (mt >> 3) * 4] = pk;
  }
}

// ---------------- persistent MFMA recurrent kernel -------------
#define HROW 136  // padded row stride in halfs

__global__ __launch_bounds__(512, 1) void lstm_mfma(
    const __half* __restrict__ zph, const _Float16* __restrict__ wp,
    unsigned long long* __restrict__ hx,  // [TT][8][4][64], sentinel-filled
    float* __restrict__ out) {
  const int blk = blockIdx.x;  // 0..31
  const int rgr = blk >> 2;    // row group 0..7 (rows 8*rgr .. +7)
  const int bg = blk & 3;      // batch group 0..3 (b = 2*bg, 2*bg+1)
  const int R0 = rgr * 8;
  const int tid = threadIdx.x;
  const int wv = tid >> 6;  // wave 0..7
  const int L = tid & 63;
  const int quad = L >> 4;
  const int l15 = L & 15;
  const int rl = l15 >> 1;  // cell row-local 0..7
  const int bl = l15 & 1;   // cell batch-local 0..1
  const int b = bg * 2 + bl;
  const int r = R0 + rl;
  const int uq0 = 16 * wv + quad * 4;     // D-side unit base (+reg)
  const int zoff = (4 * wv + quad) * 16;  // zp contiguous 16-half group

  // double-buffered: slot s holds row R0-1+s (s=0..8), per b-local
  __shared__ _Float16 h_lds[2][9 * 2 * HROW];
  for (int i = tid; i < (2 * 9 * 2 * HROW) / 2; i += 512)
    ((unsigned*)h_lds)[i] = 0u;

  // ---- weights as A-fragments, loaded once ----
  v8h wfrag[4][8];
  {
    const v8h* wp8 = (const v8h*)wp;
#pragma unroll
    for (int g = 0; g < 4; g++)
#pragma unroll
      for (int kt = 0; kt < 8; kt++)
        wfrag[g][kt] = wp8[((size_t)((8 * g + wv) * 8 + kt)) * 64 + L];
  }

  float c[4] = {0.f, 0.f, 0.f, 0.f};
  float4 outb[4];  // shift-window out buffer (w-3..w per cell)
#pragma unroll
  for (int i = 0; i < 4; i++) outb[i] = make_float4(0.f, 0.f, 0.f, 0.f);

  const int ebl = L >> 5;       // boundary consumer: b-local
  const int eu = (L & 31) * 4;  // boundary consumer: unit base
  const int exp_idx = bl * 32 + 4 * wv + quad;  // producer slot (l15>=14)

  const bool is_cons = (wv == 0) && (rgr > 0);

  // ---- incremental pointers ----
  const __half* zpp = zph + ((size_t)b * HH + r) * WW * 512 + zoff;
  const __half* zbias = zph + (size_t)BB * HH * WW * 512 + zoff;
  const unsigned long long* ca =
      hx + (((size_t)(rgr > 0 ? rgr - 1 : 0) * 4 + bg) * 64 + L);  // hx[t]
  unsigned long long* pa = hx + (((size_t)rgr * 4 + bg) * 64 + exp_idx);
  float* op0 = out + (((size_t)b * HID + uq0 + 0) * HH + r) * WW;
  float* op1 = out + (((size_t)b * HID + uq0 + 1) * HH + r) * WW;
  float* op2 = out + (((size_t)b * HID + uq0 + 2) * HH + r) * WW;
  float* op3 = out + (((size_t)b * HID + uq0 + 3) * HH + r) * WW;

  // ---- zp for t=0 (w0 = -r: in-band only for r==0) ----
  union ZU {
    uint4 q[2];
    __half h[16];  // h[g*4 + rg2]
  } zu;
  {
    const uint4* p0 = (const uint4*)((r == 0) ? zpp : zbias);
    zu.q[0] = p0[0];
    zu.q[1] = p0[1];
  }
  int wn = 1 - r;                               // next-step w
  const __half* zcur = zpp + (ptrdiff_t)wn * 512;

  // ---- boundary pipeline: pend = load of hx[t=0] ----
  unsigned long long pend = 0ull;
  if (is_cons) {
    pend = __hip_atomic_load(ca, __ATOMIC_RELAXED, __HIP_MEMORY_SCOPE_AGENT);
  }

  __syncthreads();

  for (int t = 0; t < TT; t++) {
    const int rb = t & 1;
    const int wb = rb ^ 1;

    // ---- issue next boundary load (hx[t+1], consumed end of t+1) ----
    unsigned long long newp = 0ull;
    if (is_cons && (t + 1) < TT) {
      newp = __hip_atomic_load(ca + 2048, __ATOMIC_RELAXED,
                               __HIP_MEMORY_SCOPE_AGENT);
    }

    // ---- MFMA: kt 0..3 -> rows r-1 (slot rl); kt 4..7 -> rows r (slot rl+1)
    v4f acc[4];
#pragma unroll
    for (int g = 0; g < 4; g++) acc[g] = (v4f){0.f, 0.f, 0.f, 0.f};
#pragma unroll
    for (int kt = 0; kt < 8; kt++) {
      const int slot = (kt < 4) ? rl : (rl + 1);
      v8h bf = *(const v8h*)&h_lds[rb][(slot * 2 + bl) * HROW +
                                       (kt & 3) * 32 + quad * 8];
#pragma unroll
      for (int g = 0; g < 4; g++)
        acc[g] = __builtin_amdgcn_mfma_f32_16x16x32_f16(wfrag[g][kt], bf,
                                                        acc[g], 0, 0, 0);
    }

    // ---- gates (bias pre-folded into zu) ----
    const int w = t - r;
    const bool inband = (w >= 0) && (w < WW);
    float hv[4];
#pragma unroll
    for (int rg2 = 0; rg2 < 4; rg2++) {
      float z0 = acc[0][rg2] + __half2float(zu.h[0 * 4 + rg2]);
      float z1 = acc[1][rg2] + __half2float(zu.h[1 * 4 + rg2]);
      float z2 = acc[2][rg2] + __half2float(zu.h[2 * 4 + rg2]);
      float z3 = acc[3][rg2] + __half2float(zu.h[3 * 4 + rg2]);
      float iv = fsig(z0);
      float fv = fsig(z1);
      float ov = fsig(z2);
      float gv = ftanh_(z3);
      c[rg2] = fv * c[rg2] + iv * gv;
      hv[rg2] = ov * ftanh_(c[rg2]);
    }

    // ---- h(t) -> wb slots 1..8 (LDS, 8B per lane) ----
    __half2 plo = __floats2half2_rn(hv[0], hv[1]);
    __half2 phi = __floats2half2_rn(hv[2], hv[3]);
    {
      uint2 pk;
      pk.x = *(unsigned*)&plo;
      pk.y = *(unsigned*)&phi;
      *(uint2*)&h_lds[wb][((rl + 1) * 2 + bl) * HROW + uq0] = pk;
    }

    // ---- export h(t)[R0+7]: fire-and-forget (data == flag, no drain) ----
    if (rgr < 7 && l15 >= 14) {
      unsigned long long pk =
          ((unsigned long long)*(unsigned*)&phi << 32) | *(unsigned*)&plo;
      __hip_atomic_store(pa, pk, __ATOMIC_RELAXED, __HIP_MEMORY_SCOPE_AGENT);
    }
    pa += 2048;

    // ---- out shift-window; coalesced 16B flush every 4 steps per cell ----
#pragma unroll
    for (int rg2 = 0; rg2 < 4; rg2++) {
      outb[rg2].x = outb[rg2].y;
      outb[rg2].y = outb[rg2].z;
      outb[rg2].z = outb[rg2].w;
      outb[rg2].w = hv[rg2];
    }
    if (inband && (w & 3) == 3) {
      *(float4*)op0 = outb[0];
      *(float4*)op1 = outb[1];
      *(float4*)op2 = outb[2];
      *(float4*)op3 = outb[3];
      op0 += 4;
      op1 += 4;
      op2 += 4;
      op3 += 4;
    }

    // ---- zp prefetch for t+1 (contiguous 32B; bias slot when out-of-band) --
    {
      const uint4* p =
          (const uint4*)((wn >= 0 && wn < WW) ? zcur : zbias);
      zu.q[0] = p[0];
      zu.q[1] = p[1];
      wn++;
      zcur += 512;
    }

    // ---- validate pend (hx[t] = h(t)[R0-1]), write to wb slot 0 ----
    if (is_cons) {
      while (__ballot(pend == SENT64) != 0ull) {
        __builtin_amdgcn_s_sleep(1);
        pend = __hip_atomic_load(ca, __ATOMIC_RELAXED,
                                 __HIP_MEMORY_SCOPE_AGENT);
      }
      *(unsigned long long*)&h_lds[wb][(0 * 2 + ebl) * HROW + eu] = pend;
      pend = newp;
    }
    ca += 2048;

    __syncthreads();  // wb complete; rb free for rewrite next step
  }
}

// ================= round-1 fallback path (proven correct) =================
__global__ __launch_bounds__(256) void transpose_x(const float* __restrict__ x,
                                                   float* __restrict__ xT) {
  int b = blockIdx.x >> 6;
  int r = blockIdx.x & 63;
  __shared__ float tile[32][65];
  for (int cc = 0; cc < 4; cc++) {
    int cl = threadIdx.x >> 6;
    int w = threadIdx.x & 63;
#pragma unroll
    for (int k = 0; k < 8; k++) {
      int c_loc = k * 4 + cl;
      int c = cc * 32 + c_loc;
      tile[c_loc][w] = x[(((size_t)b * 128 + c) * HH + r) * WW + w];
    }
    __syncthreads();
    int cs = threadIdx.x & 31;
    int wp = threadIdx.x >> 5;
#pragma unroll
    for (int k = 0; k < 8; k++) {
      int w2 = wp * 8 + k;
      xT[(((size_t)b * HH + r) * WW + w2) * 128 + cc * 32 + cs] = tile[cs][w2];
    }
    __syncthreads();
  }
}

__global__ __launch_bounds__(256) void step_kernel(
    const float* __restrict__ x, const float* __restrict__ xT, int use_xT,
    const float* __restrict__ w_is, const float* __restrict__ b_is,
    const float* __restrict__ w_ss, const float* __restrict__ b_ss,
    const float* __restrict__ h_prev, float* __restrict__ h_next,
    float* __restrict__ c_state, float* __restrict__ out, int t) {
  const int rg = blockIdx.x;
  const int q = blockIdx.y;
  const int r0 = rg * 2;
  const int tid = threadIdx.x;
  const int o_loc = tid & 63;
  const int k4 = tid >> 6;
  const int g_ = o_loc >> 4;
  const int u_ = o_loc & 15;
  const int O = g_ * 128 + q * 16 + u_;
  const int i0 = k4 * 32;

  __shared__ __align__(16) float h_in[3][BB][HID];
  __shared__ float zred[16][4][65];

  for (int idx = tid; idx < 3 * BB * HID; idx += 256) {
    int row_sel = idx >> 10;
    int rem = idx & 1023;
    int b = rem >> 7;
    int u = rem & 127;
    int rr = r0 - 1 + row_sel;
    h_in[row_sel][b][u] = (rr >= 0) ? h_prev[((size_t)b * HH + rr) * HID + u] : 0.0f;
  }

  float wr0[32], wr1[32], wz[32];
  {
    const float4* wss4 = (const float4*)(w_ss + ((size_t)O * 128 + i0) * 2);
#pragma unroll
    for (int j = 0; j < 16; j++) {
      float4 v = wss4[j];
      wr0[2 * j] = v.x;
      wr1[2 * j] = v.y;
      wr0[2 * j + 1] = v.z;
      wr1[2 * j + 1] = v.w;
    }
    const float4* wis4 = (const float4*)(w_is + (size_t)O * 128 + i0);
#pragma unroll
    for (int j = 0; j < 8; j++) {
      float4 v = wis4[j];
      wz[4 * j] = v.x;
      wz[4 * j + 1] = v.y;
      wz[4 * j + 2] = v.z;
      wz[4 * j + 3] = v.w;
    }
  }

  __syncthreads();

  float acc[2][BB];
#pragma unroll
  for (int rl = 0; rl < 2; rl++)
#pragma unroll
    for (int b = 0; b < BB; b++) acc[rl][b] = 0.0f;

#pragma unroll
  for (int jb = 0; jb < 8; jb++) {
    int ib = i0 + jb * 4;
#pragma unroll
    for (int b = 0; b < BB; b++) {
      const float4 hm4 = *(const float4*)&h_in[0][b][ib];
      const float4 hc4 = *(const float4*)&h_in[1][b][ib];
      const float4 hp4 = *(const float4*)&h_in[2][b][ib];
      const float* hm = (const float*)&hm4;
      const float* hc = (const float*)&hc4;
      const float* hq = (const float*)&hp4;
#pragma unroll
      for (int jj = 0; jj < 4; jj++) {
        float w0v = wr0[jb * 4 + jj];
        float w1v = wr1[jb * 4 + jj];
        acc[0][b] += w0v * hm[jj] + w1v * hc[jj];
        acc[1][b] += w0v * hc[jj] + w1v * hq[jj];
      }
    }
  }

#pragma unroll
  for (int rl = 0; rl < 2; rl++) {
    int rr = r0 + rl;
    int wcol = t - rr;
    if (wcol >= 0 && wcol < WW) {
      if (use_xT) {
        for (int b = 0; b < BB; b++) {
          const float4* xp =
              (const float4*)(xT + (((size_t)b * HH + rr) * WW + wcol) * 128 + i0);
#pragma unroll
          for (int j = 0; j < 8; j++) {
            float4 v = xp[j];
            acc[rl][b] += wz[4 * j] * v.x + wz[4 * j + 1] * v.y +
                          wz[4 * j + 2] * v.z + wz[4 * j + 3] * v.w;
          }
        }
      } else {
        for (int b = 0; b < BB; b++) {
          const float* xb = x + (((size_t)b * 128 + i0) * HH + rr) * WW + wcol;
#pragma unroll
          for (int j = 0; j < 32; j++) {
            acc[rl][b] += wz[j] * xb[(size_t)j * HH * WW];
          }
        }
      }
    }
  }

#pragma unroll
  for (int rl = 0; rl < 2; rl++)
#pragma unroll
    for (int b = 0; b < BB; b++) zred[rl * 8 + b][k4][o_loc] = acc[rl][b];
  __syncthreads();

  {
    int u = tid >> 4;
    int cell = tid & 15;
    int rl = cell >> 3;
    int b = cell & 7;
    int rr = r0 + rl;
    float z[4];
#pragma unroll
    for (int gg = 0; gg < 4; gg++) {
      int ol = gg * 16 + u;
      float s = zred[cell][0][ol] + zred[cell][1][ol] + zred[cell][2][ol] +
                zred[cell][3][ol];
      int Og = gg * 128 + q * 16 + u;
      z[gg] = s + b_is[Og] + b_ss[Og];
    }
    float iv = 1.0f / (1.0f + expf(-z[0]));
    float fv = 1.0f / (1.0f + expf(-z[1]));
    float ov = 1.0f / (1.0f + expf(-z[2]));
    float gv = tanhf(z[3]);
    int U = q * 16 + u;
    size_t sidx = ((size_t)b * HH + rr) * HID + U;
    float cv = c_state[sidx];
    float cn = fv * cv + iv * gv;
    c_state[sidx] = cn;
    float hn = ov * tanhf(cn);
    h_next[sidx] = hn;
    int wcol = t - rr;
    if (wcol >= 0 && wcol < WW) {
      out[(((size_t)b * HID + U) * HH + rr) * WW + wcol] = hn;
    }
  }
}

extern "C" void kernel_launch(void* const* d_in, const int* in_sizes, int n_in,
                              void* d_out, int out_size, void* d_ws,
                              size_t ws_size, hipStream_t stream) {
  const float* x = (const float*)d_in[0];
  const float* w_is = (const float*)d_in[1];
  const float* b_is = (const float*)d_in[2];
  const float* w_ss = (const float*)d_in[3];
  const float* b_ss = (const float*)d_in[4];
  float* outp = (float*)d_out;

  // zph has one extra 512-half bias slot at pos = B*H*W
  const size_t zph_bytes = ((size_t)BB * HH * WW * 512 + 512) * 2;
  const size_t wp_bytes = (size_t)512 * 256 * 2;    // 256 KiB
  const size_t wisa_bytes = (size_t)512 * 128 * 2;  // 128 KiB
  const size_t hx_bytes = (size_t)TT * 8 * 4 * 64 * 8;
  const size_t bsum_bytes = 512 * sizeof(float);
  const size_t need = zph_bytes + wp_bytes + wisa_bytes + hx_bytes + bsum_bytes;

  char* ws = (char*)d_ws;
  if (ws_size >= need) {
    __half* zph = (__half*)ws;
    _Float16* wpp = (_Float16*)(ws + zph_bytes);
    _Float16* wisa = (_Float16*)(ws + zph_bytes + wp_bytes);
    unsigned long long* hx =
        (unsigned long long*)(ws + zph_bytes + wp_bytes + wisa_bytes);
    float* bsum512 =
        (float*)(ws + zph_bytes + wp_bytes + wisa_bytes + hx_bytes);

    hipMemsetAsync(hx, 0xFF, hx_bytes, stream);  // sentinel = all-ones (-NaN)
    // prep covers 131072+65536+512+512 = 197632 items -> 772 blocks
    prep_w2<<<dim3(772), 256, 0, stream>>>(w_ss, w_is, b_is, b_ss, wpp, wisa,
                                           zph, bsum512);
    zpre_mfma<<<dim3(BB * HH), 256, 0, stream>>>(x, wisa, bsum512, zph);
    lstm_mfma<<<dim3(32), 512, 0, stream>>>(zph, wpp, hx, outp);
  } else {
    // -------- round-1 fallback --------
    const size_t xT_elems = (size_t)BB * HH * WW * 128;
    const size_t st_elems = (size_t)BB * HH * HID;
    const size_t need_xT = (xT_elems + 3 * st_elems) * sizeof(float);
    float* wsf = (float*)d_ws;
    float* xT = nullptr;
    float* st;
    int use_xT = 0;
    if (ws_size >= need_xT) {
      use_xT = 1;
      xT = wsf;
      st = wsf + xT_elems;
    } else {
      st = wsf;
    }
    float* h0 = st;
    float* h1 = st + st_elems;
    float* cb = st + 2 * st_elems;
    hipMemsetAsync(st, 0, 3 * st_elems * sizeof(float), stream);
    if (use_xT) transpose_x<<<dim3(BB * HH), 256, 0, stream>>>(x, xT);
    for (int t = 0; t < TT; t++) {
      float* hp = (t & 1) ? h1 : h0;
      float* hn = (t & 1) ? h0 : h1;
      step_kernel<<<dim3(32, 8), 256, 0, stream>>>(x, xT, use_xT, w_is, b_is,
                                                   w_ss, b_ss, hp, hn, cb, outp,
                                                   t);
    }
  }
}

// Round 14
// 339.510 us; speedup vs baseline: 1.0363x; 1.0363x over previous
//
#include <hip/hip_runtime.h>
#include <hip/hip_fp16.h>
#include <math.h>

// DiagonalLSTM: B=8, Cin=HID=128, H=64, W=64, K=2, T = 2W-1 = 127 steps.
//
// Round 14 design (round 13 + serial-chain cuts):
//   - clamp-free fsig/ftanh: fsig = rcp(1+exp2(-1.4427x)) (saturates, no NaN);
//     ftanh = 1 - 2*rcp(1+exp2(2.8854x)) (NaN-free at +/-inf, unlike the
//     (e-1)/(e+1) form) -> 2 fewer ops on every serial gate chain.
//   - zu->float conversion hoisted before the MFMA loop (cvts co-issue under
//     MFMA instead of sitting on the post-MFMA critical path).
//   - hx sentinel fill folded into prep_w2 (one fewer stream op).
//   - otherwise the proven R10/R12/R13 loop: 32 blocks x 512 thr, sentinel hx
//     exchange (fire-and-forget, data==flag, zero drains), 1 barrier/step,
//     boundary+zp prefetched 1 step ahead, bias folded into zph, incremental
//     pointers, MFMA intrinsics, reg-buffered out stores.

#define HID 128
#define BB 8
#define HH 64
#define WW 64
#define TT 127

typedef _Float16 v8h __attribute__((ext_vector_type(8)));
typedef float v4f __attribute__((ext_vector_type(4)));

#define SENT64 0xFFFFFFFFFFFFFFFFULL  // 4x f16 -NaN (0xFF fill pattern)

__device__ __forceinline__ float fsig(float x) {
  // saturates correctly at +/-inf without clamping; never NaN
  float e = __builtin_amdgcn_exp2f(x * -1.44269504f);
  return __builtin_amdgcn_rcpf(1.f + e);
}
__device__ __forceinline__ float ftanh_(float x) {
  // 1 - 2/(1+exp2(2x*log2e)): NaN-free at +/-inf (unlike (e-1)/(e+1))
  float e = __builtin_amdgcn_exp2f(x * 2.88539009f);
  return __builtin_fmaf(-2.f, __builtin_amdgcn_rcpf(1.f + e), 1.f);
}

// ---- prep_w2: w_ss frags + w_is frags + zph bias slot + bsum + hx fill ----
__global__ __launch_bounds__(256) void prep_w2(const float* __restrict__ w_ss,
                                               const float* __restrict__ w_is,
                                               const float* __restrict__ b_is,
                                               const float* __restrict__ b_ss,
                                               _Float16* __restrict__ wp,
                                               _Float16* __restrict__ wisa,
                                               __half* __restrict__ zph,
                                               float* __restrict__ bsum512,
                                               unsigned long long* __restrict__ hx) {
  int idx = blockIdx.x * 256 + threadIdx.x;
  if (idx < 131072) {
    // w_ss -> Wcat(512x256) A-frags: wp[(((mt*8+kt)*64+L)*8+j)]
    int j = idx & 7;
    int L = (idx >> 3) & 63;
    int kt = (idx >> 9) & 7;
    int mt = idx >> 12;  // 0..31
    int O = mt * 16 + (L & 15);
    int k = kt * 32 + ((L >> 4) & 3) * 8 + j;
    float v = (k < 128) ? w_ss[(size_t)O * 256 + k * 2]
                        : w_ss[(size_t)O * 256 + (k - 128) * 2 + 1];
    wp[idx] = (_Float16)v;
  } else if (idx < 196608) {
    // w_is (512x128) A-frags: wisa[(((mt*4+kt)*64+L)*8+j)]
    int i2 = idx - 131072;
    int j = i2 & 7;
    int L = (i2 >> 3) & 63;
    int kt = (i2 >> 9) & 3;
    int mt = i2 >> 11;  // 0..31
    int O = mt * 16 + (L & 15);
    int k = kt * 32 + ((L >> 4) & 3) * 8 + j;
    wisa[i2] = (_Float16)w_is[(size_t)O * 128 + k];
  } else if (idx < 197120) {
    // zph bias slot: layout idx2 = (u>>2)*16 + g*4 + (u&3)
    int idx2 = idx - 196608;  // 0..511
    int g = (idx2 >> 2) & 3;
    int u = (idx2 >> 4) * 4 + (idx2 & 3);
    int O = g * 128 + u;
    zph[(size_t)BB * HH * WW * 512 + idx2] = __float2half(b_is[O] + b_ss[O]);
  } else if (idx < 197632) {
    int O = idx - 197120;
    bsum512[O] = b_is[O] + b_ss[O];
  } else if (idx < 197632 + 130048) {
    // hx sentinel fill: 260096 u64 as 130048 x 16B
    int j = idx - 197632;
    uint4 s;
    s.x = 0xFFFFFFFFu;
    s.y = 0xFFFFFFFFu;
    s.z = 0xFFFFFFFFu;
    s.w = 0xFFFFFFFFu;
    ((uint4*)hx)[j] = s;
  }
}

// ---- zpre_mfma: zph[pos*512 + (u>>2)*16 + g*4 + (u&3)] = z + bias ----
__global__ __launch_bounds__(256) void zpre_mfma(const float* __restrict__ x,
                                                 const _Float16* __restrict__ wisa,
                                                 const float* __restrict__ bsum512,
                                                 __half* __restrict__ zph) {
  const int b = blockIdx.x >> 6;
  const int r = blockIdx.x & 63;
  const int tid = threadIdx.x;
  const int wv = tid >> 6;  // 0..3 -> ntile
  const int L = tid & 63;
  const int quad = L >> 4;
  const int l15 = L & 15;

  __shared__ _Float16 xt[64][136];  // [w][c] f16, padded
  __shared__ float bs[512];

  if (tid < 128) {
    *(float4*)&bs[tid * 4] = *(const float4*)&bsum512[tid * 4];
  }
  // stage x(b,:,r,:) -> xt transposed; coalesced 16-lane c-row reads
  {
    const int cw = tid >> 4;        // c within pass
    const int w4 = (tid & 15) * 4;  // w base
#pragma unroll
    for (int p = 0; p < 8; p++) {
      int c = p * 16 + cw;
      float4 v = *(const float4*)&x[(((size_t)b * 128 + c) * HH + r) * WW + w4];
      xt[w4 + 0][c] = (_Float16)v.x;
      xt[w4 + 1][c] = (_Float16)v.y;
      xt[w4 + 2][c] = (_Float16)v.z;
      xt[w4 + 3][c] = (_Float16)v.w;
    }
  }
  __syncthreads();

  const int wcol = wv * 16 + l15;  // B-side n
  v8h bf[4];
#pragma unroll
  for (int kt = 0; kt < 4; kt++)
    bf[kt] = *(const v8h*)&xt[wcol][kt * 32 + quad * 8];

  const size_t pos = ((size_t)b * HH + r) * WW + wcol;
  const v8h* wa8 = (const v8h*)wisa;

#pragma unroll 4
  for (int mt = 0; mt < 32; mt++) {
    v4f acc = (v4f){0.f, 0.f, 0.f, 0.f};
#pragma unroll
    for (int kt = 0; kt < 4; kt++) {
      v8h af = wa8[((size_t)mt * 4 + kt) * 64 + L];
      acc = __builtin_amdgcn_mfma_f32_16x16x32_f16(af, bf[kt], acc, 0, 0, 0);
    }
    // O = mt*16 + quad*4 + reg; add bias, pack, store
    float4 bv = *(float4*)&bs[mt * 16 + quad * 4];
    __half2 lo = __floats2half2_rn(acc[0] + bv.x, acc[1] + bv.y);
    __half2 hi = __floats2half2_rn(acc[2] + bv.z, acc[3] + bv.w);
    uint2 pk;
    pk.x = *(unsigned*)&lo;
    pk.y = *(unsigned*)&hi;
    *(uint2*)&zph[pos * 512 + ((mt & 7) * 4 + quad) * 16 + (mt >> 3) * 4] = pk;
  }
}

// ---------------- persistent MFMA recurrent kernel -------------
#define HROW 136  // padded row stride in halfs

__global__ __launch_bounds__(512, 1) void lstm_mfma(
    const __half* __restrict__ zph, const _Float16* __restrict__ wp,
    unsigned long long* __restrict__ hx,  // [TT][8][4][64], sentinel-filled
    float* __restrict__ out) {
  const int blk = blockIdx.x;  // 0..31
  const int rgr = blk >> 2;    // row group 0..7 (rows 8*rgr .. +7)
  const int bg = blk & 3;      // batch group 0..3 (b = 2*bg, 2*bg+1)
  const int R0 = rgr * 8;
  const int tid = threadIdx.x;
  const int wv = tid >> 6;  // wave 0..7
  const int L = tid & 63;
  const int quad = L >> 4;
  const int l15 = L & 15;
  const int rl = l15 >> 1;  // cell row-local 0..7
  const int bl = l15 & 1;   // cell batch-local 0..1
  const int b = bg * 2 + bl;
  const int r = R0 + rl;
  const int uq0 = 16 * wv + quad * 4;     // D-side unit base (+reg)
  const int zoff = (4 * wv + quad) * 16;  // zp contiguous 16-half group

  // double-buffered: slot s holds row R0-1+s (s=0..8), per b-local
  __shared__ _Float16 h_lds[2][9 * 2 * HROW];
  for (int i = tid; i < (2 * 9 * 2 * HROW) / 2; i += 512)
    ((unsigned*)h_lds)[i] = 0u;

  // ---- weights as A-fragments, loaded once ----
  v8h wfrag[4][8];
  {
    const v8h* wp8 = (const v8h*)wp;
#pragma unroll
    for (int g = 0; g < 4; g++)
#pragma unroll
      for (int kt = 0; kt < 8; kt++)
        wfrag[g][kt] = wp8[((size_t)((8 * g + wv) * 8 + kt)) * 64 + L];
  }

  float c[4] = {0.f, 0.f, 0.f, 0.f};
  float4 outb[4];  // shift-window out buffer (w-3..w per cell)
#pragma unroll
  for (int i = 0; i < 4; i++) outb[i] = make_float4(0.f, 0.f, 0.f, 0.f);

  const int ebl = L >> 5;       // boundary consumer: b-local
  const int eu = (L & 31) * 4;  // boundary consumer: unit base
  const int exp_idx = bl * 32 + 4 * wv + quad;  // producer slot (l15>=14)

  const bool is_cons = (wv == 0) && (rgr > 0);

  // ---- incremental pointers ----
  const __half* zpp = zph + ((size_t)b * HH + r) * WW * 512 + zoff;
  const __half* zbias = zph + (size_t)BB * HH * WW * 512 + zoff;
  const unsigned long long* ca =
      hx + (((size_t)(rgr > 0 ? rgr - 1 : 0) * 4 + bg) * 64 + L);  // hx[t]
  unsigned long long* pa = hx + (((size_t)rgr * 4 + bg) * 64 + exp_idx);
  float* op0 = out + (((size_t)b * HID + uq0 + 0) * HH + r) * WW;
  float* op1 = out + (((size_t)b * HID + uq0 + 1) * HH + r) * WW;
  float* op2 = out + (((size_t)b * HID + uq0 + 2) * HH + r) * WW;
  float* op3 = out + (((size_t)b * HID + uq0 + 3) * HH + r) * WW;

  // ---- zp for t=0 (w0 = -r: in-band only for r==0) ----
  union ZU {
    uint4 q[2];
    __half h[16];  // h[g*4 + rg2]
  } zu;
  {
    const uint4* p0 = (const uint4*)((r == 0) ? zpp : zbias);
    zu.q[0] = p0[0];
    zu.q[1] = p0[1];
  }
  int wn = 1 - r;  // next-step w
  const __half* zcur = zpp + (ptrdiff_t)wn * 512;

  // ---- boundary pipeline: pend = load of hx[t=0] ----
  unsigned long long pend = 0ull;
  if (is_cons) {
    pend = __hip_atomic_load(ca, __ATOMIC_RELAXED, __HIP_MEMORY_SCOPE_AGENT);
  }

  __syncthreads();

  for (int t = 0; t < TT; t++) {
    const int rb = t & 1;
    const int wb = rb ^ 1;

    // ---- issue next boundary load (hx[t+1], consumed end of t+1) ----
    unsigned long long newp = 0ull;
    if (is_cons && (t + 1) < TT) {
      newp = __hip_atomic_load(ca + 2048, __ATOMIC_RELAXED,
                               __HIP_MEMORY_SCOPE_AGENT);
    }

    // ---- convert zu -> float early (co-issues under MFMA) ----
    float zf[16];
#pragma unroll
    for (int i = 0; i < 16; i++) zf[i] = __half2float(zu.h[i]);

    // ---- MFMA: kt 0..3 -> rows r-1 (slot rl); kt 4..7 -> rows r (slot rl+1)
    v4f acc[4];
#pragma unroll
    for (int g = 0; g < 4; g++) acc[g] = (v4f){0.f, 0.f, 0.f, 0.f};
#pragma unroll
    for (int kt = 0; kt < 8; kt++) {
      const int slot = (kt < 4) ? rl : (rl + 1);
      v8h bf = *(const v8h*)&h_lds[rb][(slot * 2 + bl) * HROW +
                                       (kt & 3) * 32 + quad * 8];
#pragma unroll
      for (int g = 0; g < 4; g++)
        acc[g] = __builtin_amdgcn_mfma_f32_16x16x32_f16(wfrag[g][kt], bf,
                                                        acc[g], 0, 0, 0);
    }

    // ---- gates (bias pre-folded into zph/zf) ----
    const int w = t - r;
    const bool inband = ((unsigned)w < WW);
    float hv[4];
#pragma unroll
    for (int rg2 = 0; rg2 < 4; rg2++) {
      float z0 = acc[0][rg2] + zf[0 * 4 + rg2];
      float z1 = acc[1][rg2] + zf[1 * 4 + rg2];
      float z2 = acc[2][rg2] + zf[2 * 4 + rg2];
      float z3 = acc[3][rg2] + zf[3 * 4 + rg2];
      float iv = fsig(z0);
      float fv = fsig(z1);
      float ov = fsig(z2);
      float gv = ftanh_(z3);
      c[rg2] = fv * c[rg2] + iv * gv;
      hv[rg2] = ov * ftanh_(c[rg2]);
    }

    // ---- h(t) -> wb slots 1..8 (LDS, 8B per lane) ----
    __half2 plo = __floats2half2_rn(hv[0], hv[1]);
    __half2 phi = __floats2half2_rn(hv[2], hv[3]);
    {
      uint2 pk;
      pk.x = *(unsigned*)&plo;
      pk.y = *(unsigned*)&phi;
      *(uint2*)&h_lds[wb][((rl + 1) * 2 + bl) * HROW + uq0] = pk;
    }

    // ---- export h(t)[R0+7]: fire-and-forget (data == flag, no drain) ----
    if (rgr < 7 && l15 >= 14) {
      unsigned long long pk =
          ((unsigned long long)*(unsigned*)&phi << 32) | *(unsigned*)&plo;
      __hip_atomic_store(pa, pk, __ATOMIC_RELAXED, __HIP_MEMORY_SCOPE_AGENT);
    }
    pa += 2048;

    // ---- out shift-window; coalesced 16B flush every 4 steps per cell ----
#pragma unroll
    for (int rg2 = 0; rg2 < 4; rg2++) {
      outb[rg2].x = outb[rg2].y;
      outb[rg2].y = outb[rg2].z;
      outb[rg2].z = outb[rg2].w;
      outb[rg2].w = hv[rg2];
    }
    if (inband && (w & 3) == 3) {
      *(float4*)op0 = outb[0];
      *(float4*)op1 = outb[1];
      *(float4*)op2 = outb[2];
      *(float4*)op3 = outb[3];
      op0 += 4;
      op1 += 4;
      op2 += 4;
      op3 += 4;
    }

    // ---- zp prefetch for t+1 (contiguous 32B; bias slot when out-of-band) --
    {
      const uint4* p = (const uint4*)(((unsigned)wn < WW) ? zcur : zbias);
      zu.q[0] = p[0];
      zu.q[1] = p[1];
      wn++;
      zcur += 512;
    }

    // ---- validate pend (hx[t] = h(t)[R0-1]), write to wb slot 0 ----
    if (is_cons) {
      while (__ballot(pend == SENT64) != 0ull) {
        __builtin_amdgcn_s_sleep(1);
        pend = __hip_atomic_load(ca, __ATOMIC_RELAXED,
                                 __HIP_MEMORY_SCOPE_AGENT);
      }
      *(unsigned long long*)&h_lds[wb][(0 * 2 + ebl) * HROW + eu] = pend;
      pend = newp;
    }
    ca += 2048;

    __syncthreads();  // wb complete; rb free for rewrite next step
  }
}

// ================= round-1 fallback path (proven correct) =================
__global__ __launch_bounds__(256) void transpose_x(const float* __restrict__ x,
                                                   float* __restrict__ xT) {
  int b = blockIdx.x >> 6;
  int r = blockIdx.x & 63;
  __shared__ float tile[32][65];
  for (int cc = 0; cc < 4; cc++) {
    int cl = threadIdx.x >> 6;
    int w = threadIdx.x & 63;
#pragma unroll
    for (int k = 0; k < 8; k++) {
      int c_loc = k * 4 + cl;
      int c = cc * 32 + c_loc;
      tile[c_loc][w] = x[(((size_t)b * 128 + c) * HH + r) * WW + w];
    }
    __syncthreads();
    int cs = threadIdx.x & 31;
    int wp = threadIdx.x >> 5;
#pragma unroll
    for (int k = 0; k < 8; k++) {
      int w2 = wp * 8 + k;
      xT[(((size_t)b * HH + r) * WW + w2) * 128 + cc * 32 + cs] = tile[cs][w2];
    }
    __syncthreads();
  }
}

__global__ __launch_bounds__(256) void step_kernel(
    const float* __restrict__ x, const float* __restrict__ xT, int use_xT,
    const float* __restrict__ w_is, const float* __restrict__ b_is,
    const float* __restrict__ w_ss, const float* __restrict__ b_ss,
    const float* __restrict__ h_prev, float* __restrict__ h_next,
    float* __restrict__ c_state, float* __restrict__ out, int t) {
  const int rg = blockIdx.x;
  const int q = blockIdx.y;
  const int r0 = rg * 2;
  const int tid = threadIdx.x;
  const int o_loc = tid & 63;
  const int k4 = tid >> 6;
  const int g_ = o_loc >> 4;
  const int u_ = o_loc & 15;
  const int O = g_ * 128 + q * 16 + u_;
  const int i0 = k4 * 32;

  __shared__ __align__(16) float h_in[3][BB][HID];
  __shared__ float zred[16][4][65];

  for (int idx = tid; idx < 3 * BB * HID; idx += 256) {
    int row_sel = idx >> 10;
    int rem = idx & 1023;
    int b = rem >> 7;
    int u = rem & 127;
    int rr = r0 - 1 + row_sel;
    h_in[row_sel][b][u] = (rr >= 0) ? h_prev[((size_t)b * HH + rr) * HID + u] : 0.0f;
  }

  float wr0[32], wr1[32], wz[32];
  {
    const float4* wss4 = (const float4*)(w_ss + ((size_t)O * 128 + i0) * 2);
#pragma unroll
    for (int j = 0; j < 16; j++) {
      float4 v = wss4[j];
      wr0[2 * j] = v.x;
      wr1[2 * j] = v.y;
      wr0[2 * j + 1] = v.z;
      wr1[2 * j + 1] = v.w;
    }
    const float4* wis4 = (const float4*)(w_is + (size_t)O * 128 + i0);
#pragma unroll
    for (int j = 0; j < 8; j++) {
      float4 v = wis4[j];
      wz[4 * j] = v.x;
      wz[4 * j + 1] = v.y;
      wz[4 * j + 2] = v.z;
      wz[4 * j + 3] = v.w;
    }
  }

  __syncthreads();

  float acc[2][BB];
#pragma unroll
  for (int rl = 0; rl < 2; rl++)
#pragma unroll
    for (int b = 0; b < BB; b++) acc[rl][b] = 0.0f;

#pragma unroll
  for (int jb = 0; jb < 8; jb++) {
    int ib = i0 + jb * 4;
#pragma unroll
    for (int b = 0; b < BB; b++) {
      const float4 hm4 = *(const float4*)&h_in[0][b][ib];
      const float4 hc4 = *(const float4*)&h_in[1][b][ib];
      const float4 hp4 = *(const float4*)&h_in[2][b][ib];
      const float* hm = (const float*)&hm4;
      const float* hc = (const float*)&hc4;
      const float* hq = (const float*)&hp4;
#pragma unroll
      for (int jj = 0; jj < 4; jj++) {
        float w0v = wr0[jb * 4 + jj];
        float w1v = wr1[jb * 4 + jj];
        acc[0][b] += w0v * hm[jj] + w1v * hc[jj];
        acc[1][b] += w0v * hc[jj] + w1v * hq[jj];
      }
    }
  }

#pragma unroll
  for (int rl = 0; rl < 2; rl++) {
    int rr = r0 + rl;
    int wcol = t - rr;
    if (wcol >= 0 && wcol < WW) {
      if (use_xT) {
        for (int b = 0; b < BB; b++) {
          const float4* xp =
              (const float4*)(xT + (((size_t)b * HH + rr) * WW + wcol) * 128 + i0);
#pragma unroll
          for (int j = 0; j < 8; j++) {
            float4 v = xp[j];
            acc[rl][b] += wz[4 * j] * v.x + wz[4 * j + 1] * v.y +
                          wz[4 * j + 2] * v.z + wz[4 * j + 3] * v.w;
          }
        }
      } else {
        for (int b = 0; b < BB; b++) {
          const float* xb = x + (((size_t)b * 128 + i0) * HH + rr) * WW + wcol;
#pragma unroll
          for (int j = 0; j < 32; j++) {
            acc[rl][b] += wz[j] * xb[(size_t)j * HH * WW];
          }
        }
      }
    }
  }

#pragma unroll
  for (int rl = 0; rl < 2; rl++)
#pragma unroll
    for (int b = 0; b < BB; b++) zred[rl * 8 + b][k4][o_loc] = acc[rl][b];
  __syncthreads();

  {
    int u = tid >> 4;
    int cell = tid & 15;
    int rl = cell >> 3;
    int b = cell & 7;
    int rr = r0 + rl;
    float z[4];
#pragma unroll
    for (int gg = 0; gg < 4; gg++) {
      int ol = gg * 16 + u;
      float s = zred[cell][0][ol] + zred[cell][1][ol] + zred[cell][2][ol] +
                zred[cell][3][ol];
      int Og = gg * 128 + q * 16 + u;
      z[gg] = s + b_is[Og] + b_ss[Og];
    }
    float iv = 1.0f / (1.0f + expf(-z[0]));
    float fv = 1.0f / (1.0f + expf(-z[1]));
    float ov = 1.0f / (1.0f + expf(-z[2]));
    float gv = tanhf(z[3]);
    int U = q * 16 + u;
    size_t sidx = ((size_t)b * HH + rr) * HID + U;
    float cv = c_state[sidx];
    float cn = fv * cv + iv * gv;
    c_state[sidx] = cn;
    float hn = ov * tanhf(cn);
    h_next[sidx] = hn;
    int wcol = t - rr;
    if (wcol >= 0 && wcol < WW) {
      out[(((size_t)b * HID + U) * HH + rr) * WW + wcol] = hn;
    }
  }
}

extern "C" void kernel_launch(void* const* d_in, const int* in_sizes, int n_in,
                              void* d_out, int out_size, void* d_ws,
                              size_t ws_size, hipStream_t stream) {
  const float* x = (const float*)d_in[0];
  const float* w_is = (const float*)d_in[1];
  const float* b_is = (const float*)d_in[2];
  const float* w_ss = (const float*)d_in[3];
  const float* b_ss = (const float*)d_in[4];
  float* outp = (float*)d_out;

  // zph has one extra 512-half bias slot at pos = B*H*W
  const size_t zph_bytes = ((size_t)BB * HH * WW * 512 + 512) * 2;
  const size_t wp_bytes = (size_t)512 * 256 * 2;    // 256 KiB
  const size_t wisa_bytes = (size_t)512 * 128 * 2;  // 128 KiB
  const size_t hx_bytes = (size_t)TT * 8 * 4 * 64 * 8;
  const size_t bsum_bytes = 512 * sizeof(float);
  const size_t need = zph_bytes + wp_bytes + wisa_bytes + hx_bytes + bsum_bytes;

  char* ws = (char*)d_ws;
  if (ws_size >= need) {
    __half* zph = (__half*)ws;
    _Float16* wpp = (_Float16*)(ws + zph_bytes);
    _Float16* wisa = (_Float16*)(ws + zph_bytes + wp_bytes);
    unsigned long long* hx =
        (unsigned long long*)(ws + zph_bytes + wp_bytes + wisa_bytes);
    float* bsum512 =
        (float*)(ws + zph_bytes + wp_bytes + wisa_bytes + hx_bytes);

    // prep covers 131072+65536+512+512+130048 = 327680 items -> 1280 blocks
    prep_w2<<<dim3(1280), 256, 0, stream>>>(w_ss, w_is, b_is, b_ss, wpp, wisa,
                                            zph, bsum512, hx);
    zpre_mfma<<<dim3(BB * HH), 256, 0, stream>>>(x, wisa, bsum512, zph);
    lstm_mfma<<<dim3(32), 512, 0, stream>>>(zph, wpp, hx, outp);
  } else {
    // -------- round-1 fallback --------
    const size_t xT_elems = (size_t)BB * HH * WW * 128;
    const size_t st_elems = (size_t)BB * HH * HID;
    const size_t need_xT = (xT_elems + 3 * st_elems) * sizeof(float);
    float* wsf = (float*)d_ws;
    float* xT = nullptr;
    float* st;
    int use_xT = 0;
    if (ws_size >= need_xT) {
      use_xT = 1;
      xT = wsf;
      st = wsf + xT_elems;
    } else {
      st = wsf;
    }
    float* h0 = st;
    float* h1 = st + st_elems;
    float* cb = st + 2 * st_elems;
    hipMemsetAsync(st, 0, 3 * st_elems * sizeof(float), stream);
    if (use_xT) transpose_x<<<dim3(BB * HH), 256, 0, stream>>>(x, xT);
    for (int t = 0; t < TT; t++) {
      float* hp = (t & 1) ? h1 : h0;
      float* hn = (t & 1) ? h0 : h1;
      step_kernel<<<dim3(32, 8), 256, 0, stream>>>(x, xT, use_xT, w_is, b_is,
                                                   w_ss, b_ss, hp, hn, cb, outp,
                                                   t);
    }
  }
}